// Round 1
// baseline (97.337 us; speedup 1.0000x reference)
//
#include <hip/hip_runtime.h>

#define IN_F   1024
#define OUT_F  1024
#define BATCH  32
#define KCOEF  97
#define CHUNK  64

__global__ __launch_bounds__(256, 4)
void piecewise_kernel(const float* __restrict__ x,
                      const float* __restrict__ w,
                      float* __restrict__ out) {
    const int o = blockIdx.x;
    const int t = threadIdx.x;
    const int b = t & 31;   // batch lane
    const int g = t >> 5;   // i-group 0..7

    __shared__ float xs[CHUNK * 33];   // xT[i_local][b], padded stride 33
    __shared__ float red[256];

    const float* wbase_o = w + (long)o * (IN_F * KCOEF);

    float acc = 0.0f;

    for (int i0 = 0; i0 < IN_F; i0 += CHUNK) {
        // stage x[0..31][i0..i0+CHUNK) transposed into LDS (coalesced reads)
        for (int e = t; e < CHUNK * BATCH; e += 256) {
            int bb = e >> 6;        // 0..31
            int ii = e & 63;        // 0..63
            xs[ii * 33 + bb] = x[bb * IN_F + i0 + ii];
        }
        __syncthreads();

        const float* wchunk = wbase_o + (long)i0 * KCOEF;

        #pragma unroll 2
        for (int u = 0; u < 8; ++u) {
            const int il = u * 8 + g;                 // i_local, rows i and i+1 per wave
            float xv = xs[il * 33 + b];

            // segment id: matches ref rounding ((x+1)/2*32 == (x+1)*16 exactly)
            float s = (xv + 1.0f) * 16.0f;
            int id = (int)s;
            id = id < 0 ? 0 : (id > 31 ? 31 : id);

            // local coordinate on [-1,1]: tt = (x - x_min)*32 - 1
            float d  = xv - ((float)id * 0.0625f - 1.0f);
            float tt = fmaf(d, 32.0f, -1.0f);

            // Lagrange basis at Chebyshev-Lobatto nodes [-1,-0.5,0.5,1]
            float ap = tt + 1.0f, bp = tt + 0.5f, cm = tt - 0.5f, dm = tt - 1.0f;
            float uu = bp * cm, vv = ap * dm;
            float B0 = uu * dm * (-2.0f / 3.0f);
            float B1 = vv * cm * ( 4.0f / 3.0f);
            float B2 = vv * bp * (-4.0f / 3.0f);
            float B3 = uu * ap * ( 2.0f / 3.0f);

            const float* wr = wchunk + il * KCOEF + id * 3;
            float w0 = wr[0], w1 = wr[1], w2 = wr[2], w3 = wr[3];
            acc = fmaf(B0, w0, acc);
            acc = fmaf(B1, w1, acc);
            acc = fmaf(B2, w2, acc);
            acc = fmaf(B3, w3, acc);
        }
        __syncthreads();
    }

    // reduce the 8 group-partials per (b, o)
    red[t] = acc;
    __syncthreads();
    if (t < 32) {
        float s = red[t];
        #pragma unroll
        for (int gg = 1; gg < 8; ++gg) s += red[gg * 32 + t];
        out[t * OUT_F + o] = s;
    }
}

extern "C" void kernel_launch(void* const* d_in, const int* in_sizes, int n_in,
                              void* d_out, int out_size, void* d_ws, size_t ws_size,
                              hipStream_t stream) {
    const float* x  = (const float*)d_in[0];
    const float* w  = (const float*)d_in[1];
    float*       out = (float*)d_out;
    piecewise_kernel<<<OUT_F, 256, 0, stream>>>(x, w, out);
}